// Round 1
// 199.942 us; speedup vs baseline: 1.0213x; 1.0213x over previous
//
#include <hip/hip_runtime.h>
#include <stdint.h>

// Problem constants: N=128, T=2048, D=88
#define NN 128
#define TT 2048
#define DD 88
#define ROWS 32                      // timesteps per K1 block
#define F4_ROW 22                    // float4 per row (88 floats)
#define F4_TILE (ROWS * F4_ROW)      // 704 f4 = 11264 B per array
#define INSTR_PER_ARR 11             // 11 x 1KB global_load_lds per array
#define K1_BLOCKS (NN * TT / ROWS)   // 8192
#define PARTS_PER_N (TT / ROWS)      // 64 tp partials per n
#define CPN 8                        // tail chunk-blocks per n
#define K2_BLOCKS (NN * CPN)         // 1024

typedef float f4 __attribute__((ext_vector_type(4)));
typedef const __attribute__((address_space(1))) uint32_t guint;
typedef __attribute__((address_space(3))) uint32_t luint;

// K1: async global->LDS staging (no VGPR round-trip; all of a wave's 1KB
// loads in flight), then per-row fpfn + per-block tp partial.
// Measured best of 5 structures: 67 us ≈ 87% of the ~3 TB/s read-direction
// fabric ceiling (184 MB beyond-L2 reads), VALU/LDS/occupancy all slack.
// UNCHANGED this round — it is at its measured ceiling; the tail is not.
__global__ __launch_bounds__(256) void acc_rowstats_kernel(
    const float* __restrict__ outp, const float* __restrict__ tgt,
    float* __restrict__ fpfn, float* __restrict__ tp_part) {
  __shared__ f4 lds_o[F4_TILE];
  __shared__ f4 lds_g[F4_TILE];
  __shared__ float s_tp[4];

  const int tid = threadIdx.x;
  const int lane = tid & 63;
  const int wave = tid >> 6;
  const int blk = blockIdx.x;
  const size_t tile_f = (size_t)blk * (ROWS * DD);  // element offset of tile

  // ---- stage 22 x 1KB direct-to-LDS (waves 0,1: 6 instrs; waves 2,3: 5) ----
  for (int j = wave; j < 2 * INSTR_PER_ARR; j += 4) {
    const int is_g = (j >= INSTR_PER_ARR) ? 1 : 0;
    const int idx = j - is_g * INSTR_PER_ARR;        // wave-uniform
    const float* src = (is_g ? tgt : outp) + tile_f + idx * 256;
    float* dst = (is_g ? (float*)lds_g : (float*)lds_o) + idx * 256;
    __builtin_amdgcn_global_load_lds((guint*)src + lane * 4, (luint*)dst,
                                     16, 0, 0);
  }
  __syncthreads();  // compiler drains vmcnt before the barrier

  // ---- consume from LDS: 8 threads per row ----
  const int r = tid >> 3;  // 0..31
  const int s = tid & 7;
  float tp = 0.f;
  float x = 0.f;
#pragma unroll
  for (int j0 = 0; j0 < 3; ++j0) {
    const int j = s + j0 * 8;
    if (j < F4_ROW) {
      const f4 o = lds_o[r * F4_ROW + j];
      const f4 g = lds_g[r * F4_ROW + j];
      {
        const float pf = (o.x > 0.f) ? 1.f : 0.f;
        x += fabsf(pf - g.x);
        tp = fmaf(pf, g.x, tp);
      }
      {
        const float pf = (o.y > 0.f) ? 1.f : 0.f;
        x += fabsf(pf - g.y);
        tp = fmaf(pf, g.y, tp);
      }
      {
        const float pf = (o.z > 0.f) ? 1.f : 0.f;
        x += fabsf(pf - g.z);
        tp = fmaf(pf, g.z, tp);
      }
      {
        const float pf = (o.w > 0.f) ? 1.f : 0.f;
        x += fabsf(pf - g.w);
        tp = fmaf(pf, g.w, tp);
      }
    }
  }
  // fpfn: reduce across the 8 contiguous lanes of this row
  x += __shfl_down(x, 4, 64);
  x += __shfl_down(x, 2, 64);
  x += __shfl_down(x, 1, 64);
  if (s == 0) fpfn[(size_t)blk * ROWS + r] = x;

  // tp: wave reduce + cross-wave, deterministic per-block partial
  for (int off = 32; off > 0; off >>= 1) tp += __shfl_down(tp, off, 64);
  if (lane == 0) s_tp[wave] = tp;
  __syncthreads();
  if (tid == 0) tp_part[blk] = s_tp[0] + s_tp[1] + s_tp[2] + s_tp[3];
}

// K2 (rebuilt): 8 chunk-blocks per n instead of 1 block per n.
// Old tail was latency-bound by design: 128 blocks (half the CUs idle),
// 16 barrier-tree syncs, ratio loads gated on the Ti reduction, and 128
// serialized same-address atomics. Here:
//  - ALL global loads issue before any reduction (fpfn is a full 2048-row
//    regardless of Ti, so loads need no Ti gate; invalid t selected to 0).
//  - Ti / tp are sums of exactly-representable integers (< 2^24): any
//    reduction order is bit-exact, so shuffle reductions are safe.
//  - 2 barriers total; no atomics (deterministic K3 finish instead).
// Redundant work (each of the 8 blocks re-reduces mask + tp_part) is ~9 MB
// of L2/L3-resident reads across the whole grid — noise.
__global__ __launch_bounds__(256) void acc_chunk_kernel(
    const int* __restrict__ mask, const float* __restrict__ fpfn,
    const float* __restrict__ tp_part, float* __restrict__ accp) {
  const int b = blockIdx.x;
  const int n = b >> 3;            // CPN = 8
  const int c = b & (CPN - 1);
  const int tid = threadIdx.x;
  const int lane = tid & 63;
  const int wave = tid >> 6;
  __shared__ float s_ti[4];
  __shared__ float s_tp[4];
  __shared__ float s_a[4];

  // ---- issue every global load up front (nothing gated on reductions) ----
  const int4* m4 = (const int4*)(mask + (size_t)n * TT);
  const int4 v0 = m4[tid];
  const int4 v1 = m4[tid + 256];
  const float tpv = (tid < PARTS_PER_N) ? tp_part[n * PARTS_PER_N + tid] : 0.f;
  const int t = c * 256 + tid;
  const float fr = fpfn[(size_t)n * TT + t];

  // ---- Ti and tp: exact-integer shuffle reductions (order-insensitive) ----
  int ti = v0.x + v0.y + v0.z + v0.w + v1.x + v1.y + v1.z + v1.w;
  float tp = tpv;
  for (int off = 32; off > 0; off >>= 1) {
    ti += __shfl_down(ti, off, 64);
    tp += __shfl_down(tp, off, 64);
  }
  if (lane == 0) { s_ti[wave] = (float)ti; s_tp[wave] = tp; }
  __syncthreads();
  const float fTi = s_ti[0] + s_ti[1] + s_ti[2] + s_ti[3];  // exact (<= 2048)
  const float tpn = s_tp[0] + s_tp[1] + s_tp[2] + s_tp[3];  // exact integer
  const int Ti = (int)fTi;

  // ---- ratio for this block's 256 timesteps, then block reduction ----
  float a = (t < Ti) ? tpn / (tpn + fr) : 0.f;
  for (int off = 32; off > 0; off >>= 1) a += __shfl_down(a, off, 64);
  if (lane == 0) s_a[wave] = a;
  __syncthreads();
  if (tid == 0)
    accp[b] = (s_a[0] + s_a[1] + s_a[2] + s_a[3]) / fTi;
}

// K3: deterministic final sum of the 1024 chunk partials -> out[0].
// Replaces memset + 128 same-address atomics with one tiny dispatch.
__global__ __launch_bounds__(256) void acc_sum_kernel(
    const float* __restrict__ accp, float* __restrict__ out) {
  const int tid = threadIdx.x;
  const int lane = tid & 63;
  const int wave = tid >> 6;
  __shared__ float s_a[4];
  float a = accp[tid] + accp[tid + 256] + accp[tid + 512] + accp[tid + 768];
  for (int off = 32; off > 0; off >>= 1) a += __shfl_down(a, off, 64);
  if (lane == 0) s_a[wave] = a;
  __syncthreads();
  if (tid == 0) out[0] = s_a[0] + s_a[1] + s_a[2] + s_a[3];
}

extern "C" void kernel_launch(void* const* d_in, const int* in_sizes, int n_in,
                              void* d_out, int out_size, void* d_ws, size_t ws_size,
                              hipStream_t stream) {
  const float* output = (const float*)d_in[0];
  const float* target = (const float*)d_in[1];
  const int* mask = (const int*)d_in[2];
  float* out = (float*)d_out;

  float* tp_part = (float*)d_ws;          // K1_BLOCKS floats
  float* fpfn = tp_part + K1_BLOCKS;      // N*T floats
  float* accp = fpfn + (size_t)NN * TT;   // K2_BLOCKS floats

  acc_rowstats_kernel<<<K1_BLOCKS, 256, 0, stream>>>(output, target, fpfn, tp_part);
  acc_chunk_kernel<<<K2_BLOCKS, 256, 0, stream>>>(mask, fpfn, tp_part, accp);
  acc_sum_kernel<<<1, 256, 0, stream>>>(accp, out);
}